// Round 3
// baseline (194.288 us; speedup 1.0000x reference)
//
#include <hip/hip_runtime.h>
#include <hip/hip_bf16.h>

#define N1 8192
#define N2 8192
#define CDIM 128
#define HC 60
#define WC 80
#define HIMG 480
#define WIMG 640
#define NPIX (HC * WC)
#define INV_DENOM (1.0f / (8192.0f * 256.0f))
#define THIBITS 0x4200u     // bf16 bits of 32.0
#define NSPLIT 8            // column splits per row-stripe
#define RECW 112            // uints per row record: 96 hist + 1 cnt + 12 hilist + 3 pad
#define HI_CAP 24           // per-(row,split) hi-value capacity (mean ~2.4, >10 sigma)

using bf16x8 = __attribute__((ext_vector_type(8))) short;
using f32x4  = __attribute__((ext_vector_type(4))) float;

__device__ __forceinline__ ushort f2bf(float f) {
    union { float f; unsigned u; } x; x.f = f;
    unsigned u = x.u;
    unsigned r = (u + 0x7FFFu + ((u >> 16) & 1u)) >> 16;
    return (ushort)r;
}
__device__ __forceinline__ float bf2f(unsigned bits) {
    union { unsigned u; float f; } x; x.u = bits << 16; return x.f;
}
__device__ __forceinline__ unsigned key2bits(unsigned k) {
    return k ^ ((k & 0x8000u) ? 0x8000u : 0xFFFFu);
}
__device__ __forceinline__ unsigned bits2key(unsigned h) {
    return h ^ ((h & 0x8000u) ? 0xFFFFu : 0x8000u);
}

// ---------- fused prep: cvt A, cvt B, transpose desc2 ----------
__global__ void prep_kernel(const float* __restrict__ kp1d,
                            const float* __restrict__ kp2d,
                            const float* __restrict__ desc2,
                            ushort* __restrict__ Abf, ushort* __restrict__ Bbf,
                            float* __restrict__ d2T) {
    const int n4 = N1 * CDIM / 4;        // 262144
    int i = blockIdx.x * blockDim.x + threadIdx.x;
    if (i < n4) {
        float4 v = ((const float4*)kp1d)[i];
        ushort4 o;
        o.x = f2bf(v.x); o.y = f2bf(v.y); o.z = f2bf(v.z); o.w = f2bf(v.w);
        ((ushort4*)Abf)[i] = o;
    } else if (i < 2 * n4) {
        int k = i - n4;
        float4 v = ((const float4*)kp2d)[k];
        ushort4 o;
        o.x = f2bf(v.x); o.y = f2bf(v.y); o.z = f2bf(v.z); o.w = f2bf(v.w);
        ((ushort4*)Bbf)[k] = o;
    } else {
        int e = i - 2 * n4;
        if (e < NPIX * CDIM) {
            int c = e / NPIX;
            int p = e - c * NPIX;
            d2T[(size_t)p * CDIM + c] = desc2[e];
        }
    }
}

// ---------- positive term (coalesced, plain store) ----------
__global__ void pos_kernel(const float* __restrict__ wkp1,
                           const float* __restrict__ kp1d,
                           const float* __restrict__ desc2T,
                           float* __restrict__ ploss) {
    const int i = blockIdx.x;
    const int c = threadIdx.x;            // 128 threads = 2 waves
    float y = wkp1[2 * i], x = wkp1[2 * i + 1];
    float py = fminf(fmaxf(y / (float)(HIMG - 1) * (float)(HC - 1), 0.0f), (float)(HC - 1));
    float px = fminf(fmaxf(x / (float)(WIMG - 1) * (float)(WC - 1), 0.0f), (float)(WC - 1));
    int y0 = min(max((int)floorf(py), 0), HC - 2);
    int x0 = min(max((int)floorf(px), 0), WC - 2);
    float wy = py - (float)y0;
    float wx = px - (float)x0;
    const int p00 = y0 * WC + x0;
    float v00 = desc2T[(size_t)p00 * CDIM + c];
    float v01 = desc2T[(size_t)(p00 + 1) * CDIM + c];
    float v10 = desc2T[(size_t)(p00 + WC) * CDIM + c];
    float v11 = desc2T[(size_t)(p00 + WC + 1) * CDIM + c];
    float v = v00 * (1.0f - wy) * (1.0f - wx) + v01 * (1.0f - wy) * wx
            + v10 * wy * (1.0f - wx) + v11 * wy * wx;
    float a = kp1d[(size_t)i * CDIM + c];
    float s2 = v * v, sav = a * v;
    #pragma unroll
    for (int off = 32; off >= 1; off >>= 1) {
        s2  += __shfl_down(s2, off);
        sav += __shfl_down(sav, off);
    }
    __shared__ float p2[2], pav[2];
    int wave = threadIdx.x >> 6, lane = threadIdx.x & 63;
    if (lane == 0) { p2[wave] = s2; pav[wave] = sav; }
    __syncthreads();
    if (threadIdx.x == 0) {
        float nrm = sqrtf(p2[0] + p2[1]);
        float pd = (pav[0] + pav[1]) / fmaxf(nrm, 1e-12f);
        float l = fmaxf(1.0f - pd, 0.0f) * (256.0f / 3.0f);
        ploss[i] = l * INV_DENOM;
    }
}

// ---------- masked GEMM + in-LDS per-row histogram (R3) ----------
// R2 post-mortem: gemm was write-bound (128 MB dots at 3 TB/s, 47.5us) and
// select re-read those 128 MB only to histogram them. R3: block = 128 rows x
// 1024 cols; A fragments live in registers across the whole N loop, B comes
// straight from L2 (2 MB resident), NO staging LDS, no inner barriers. The
// epilogue bins each value into a per-row 192-bin packed-ushort LDS histogram
// (bin = bf16bits - 0x4141 for (12,32]; same bit-domain as R2) + a per-row
// hi-list (>32, exact bits, cap 24). Block writes its 128x448B record once:
// 28 MB total replaces 128 MB dots write + 128 MB select read. All atomics
// LDS-local (R1's global-atomic mistake avoided). Counts per split <= 1024 so
// packed halves can't carry. Record: [96 packed hist][cnt][24 ushort][pad].
__global__ __launch_bounds__(256, 2)
void gemm_kernel(const ushort* __restrict__ A, const ushort* __restrict__ B,
                 const float* __restrict__ wkp1, const float* __restrict__ kp2,
                 unsigned* __restrict__ parts) {
    __shared__ unsigned shist[128 * RECW];    // 56 KB -> 2 blocks/CU
    __shared__ float s_w[256];

    const int t = threadIdx.x;
    const int split = blockIdx.x;             // 0..7
    const int mtile = blockIdx.y;             // 0..63
    const int m0 = mtile * 128;

    for (int i = t; i < 128 * RECW; i += 256) shist[i] = 0u;
    s_w[t] = wkp1[2 * m0 + t];
    __syncthreads();

    const int lane = t & 63;
    const int wave = t >> 6;
    const int wm = wave >> 1, wn = wave & 1;
    const int lrow = lane & 15, quad = lane >> 4;

    // A fragments resident in registers for the whole N loop (64 VGPR)
    bf16x8 afr[4][4];
    #pragma unroll
    for (int kit = 0; kit < 4; kit++)
        #pragma unroll
        for (int mt = 0; mt < 4; mt++)
            afr[kit][mt] = *(const bf16x8*)(A
                + (size_t)(m0 + wm * 64 + mt * 16 + lrow) * CDIM + kit * 32 + quad * 8);

    const float thr = 2.0f * sqrtf(32.0f) + 0.1f;
    const float thr2 = thr * thr;
    ushort* slist16 = (ushort*)shist;

    for (int it = 0; it < 8; it++) {
        const int nbase = split * 1024 + it * 128;

        f32x4 acc[4][4];
        #pragma unroll
        for (int i = 0; i < 4; i++)
            #pragma unroll
            for (int j = 0; j < 4; j++) acc[i][j] = (f32x4){0.f, 0.f, 0.f, 0.f};

        #pragma unroll
        for (int kit = 0; kit < 4; kit++) {
            bf16x8 bfr[4];
            #pragma unroll
            for (int nt = 0; nt < 4; nt++)
                bfr[nt] = *(const bf16x8*)(B
                    + (size_t)(nbase + wn * 64 + nt * 16 + lrow) * CDIM + kit * 32 + quad * 8);
            #pragma unroll
            for (int mt = 0; mt < 4; mt++)
                #pragma unroll
                for (int nt = 0; nt < 4; nt++)
                    acc[mt][nt] = __builtin_amdgcn_mfma_f32_16x16x32_bf16(
                        afr[kit][mt], bfr[nt], acc[mt][nt], 0, 0, 0);
        }

        float ky[4], kx[4];
        #pragma unroll
        for (int nt = 0; nt < 4; nt++) {
            int j = nbase + wn * 64 + nt * 16 + lrow;
            ky[nt] = kp2[2 * j]; kx[nt] = kp2[2 * j + 1];
        }

        #pragma unroll
        for (int mt = 0; mt < 4; mt++) {
            #pragma unroll
            for (int r = 0; r < 4; r++) {
                const int il = wm * 64 + mt * 16 + quad * 4 + r;   // local row
                const float wy = s_w[2 * il], wx = s_w[2 * il + 1];
                const int ldsrow = il * RECW;
                #pragma unroll
                for (int nt = 0; nt < 4; nt++) {
                    float dy = wy - ky[nt], dx = wx - kx[nt];
                    float v = acc[mt][nt][r];
                    if (dy * dy + dx * dx <= thr2) v -= 5.0f;
                    unsigned h = (unsigned)f2bf(v);
                    unsigned u = h - 0x4141u;
                    if (u < 0xC0u) {                      // (12, 32]: bins 0..191
                        atomicAdd(&shist[ldsrow + (int)(u >> 1)],
                                  1u << ((u & 1u) * 16u));
                    } else if (u < 0x3EBFu) {             // > 32.0: hi-list
                        unsigned id = atomicAdd(&shist[ldsrow + 96], 1u);
                        if (id < HI_CAP)
                            slist16[(ldsrow + 97) * 2 + id] = (ushort)h;
                    }
                }
            }
        }
    }
    __syncthreads();

    const uint4* src = (const uint4*)shist;
    uint4* dst = (uint4*)(parts + (size_t)(mtile * NSPLIT + split) * 128 * RECW);
    for (int i = t; i < 128 * RECW / 4; i += 256) dst[i] = src[i];
}

// ---------- per-row top-256 hinge from merged partial histograms (R3) ----------
// One wave per row. Merge 8 partial records (packed uint adds -- halves sum to
// <=8192, no carry), redistribute bins via 768B LDS, then R2's suffix-scan /
// threshold-find / f64 per-bin + hi sums verbatim (bit-identical result;
// deterministic despite nondeterministic hi-append order: f64 sums of <=255
// f32 terms are exact). Fallback (tot<256 | nhi>255 | hi overflow; all >10
// sigma events) recomputes the row's dots on the fly (scalar FMA) -- dots is
// gone entirely.
__global__ __launch_bounds__(256)
void select_kernel(const unsigned* __restrict__ parts,
                   const ushort* __restrict__ A, const ushort* __restrict__ B,
                   const float* __restrict__ wkp1, const float* __restrict__ kp2,
                   float* __restrict__ rloss) {
    const int wave = threadIdx.x >> 6, l = threadIdx.x & 63;
    const int g = blockIdx.x * 4 + wave;          // global row
    const int mtile = g >> 7, rowin = g & 127;

    __shared__ unsigned merged_s[4][192];
    unsigned* merged = merged_s[wave];

    unsigned w0 = 0, w1 = 0, nhi = 0;
    bool hov = false;
    #pragma unroll
    for (int rg = 0; rg < NSPLIT; rg++) {
        const unsigned* rp = parts + (size_t)((mtile * NSPLIT + rg) * 128 + rowin) * RECW;
        w0 += rp[l];
        if (l < 32) w1 += rp[64 + l];
        unsigned cr = rp[96];
        nhi += cr;
        hov |= (cr > HI_CAP);
    }
    merged[2 * l]     = w0 & 0xFFFFu;
    merged[2 * l + 1] = w0 >> 16;
    if (l < 32) {
        merged[128 + 2 * l] = w1 & 0xFFFFu;
        merged[129 + 2 * l] = w1 >> 16;
    }
    __syncthreads();     // all 4 waves reach this exactly once; none after

    unsigned c0 = merged[l], c1 = merged[64 + l], c2 = merged[128 + l];

    // inclusive suffix-scan across lanes for each 64-bin chunk
    unsigned s0i = c0, s1i = c1, s2i = c2;
    #pragma unroll
    for (int off = 1; off < 64; off <<= 1) {
        unsigned t0 = __shfl_down(s0i, off);
        unsigned t1 = __shfl_down(s1i, off);
        unsigned t2 = __shfl_down(s2i, off);
        if (l + off < 64) { s0i += t0; s1i += t1; s2i += t2; }
    }
    const unsigned T0 = __shfl(s0i, 0), T1 = __shfl(s1i, 0), T2 = __shfl(s2i, 0);
    const unsigned tot = nhi + T0 + T1 + T2;      // count of values > 12.0

    const unsigned Ce0 = nhi + T1 + T2 + (s0i - c0);
    const unsigned Ce1 = nhi + T2 + (s1i - c1);
    const unsigned Ce2 = nhi + (s2i - c2);

    const bool ok = (tot >= 256u) && (nhi <= 255u) && !hov;

    const float thr = 2.0f * sqrtf(32.0f) + 0.1f;
    const float thr2 = thr * thr;

    unsigned ktb;            // bf16 bits of 256th-largest (attained)
    double s = 0.0;
    int cgt = 0;

    if (ok) {
        unsigned long long m0 = __ballot(Ce0 < 256u);
        unsigned long long m1 = __ballot(Ce1 < 256u);
        unsigned long long m2 = __ballot(Ce2 < 256u);
        int bmin; unsigned cg;
        if (m0) { int fl = __ffsll(m0) - 1; bmin = fl;       cg = __shfl(Ce0, fl); }
        else if (m1) { int fl = __ffsll(m1) - 1; bmin = 64 + fl;  cg = __shfl(Ce1, fl); }
        else { int fl = __ffsll(m2) - 1; bmin = 128 + fl; cg = __shfl(Ce2, fl); }
        ktb = 0x4141u + (unsigned)bmin;
        cgt = (int)cg;
        // per-bin hinge sums: cnt * (f32)(val - 0.2f), exact in f64
        if (l > bmin)       s += (double)c0 * (double)(bf2f(0x4141u + (unsigned)l) - 0.2f);
        if (64 + l > bmin)  s += (double)c1 * (double)(bf2f(0x4141u + 64u + (unsigned)l) - 0.2f);
        if (128 + l > bmin) s += (double)c2 * (double)(bf2f(0x4141u + 128u + (unsigned)l) - 0.2f);
        // hi values (> 32.0): all above threshold
        #pragma unroll
        for (int rg = 0; rg < NSPLIT; rg++) {
            const unsigned* rp = parts + (size_t)((mtile * NSPLIT + rg) * 128 + rowin) * RECW;
            unsigned cr = rp[96];                  // <= HI_CAP here (ok path)
            const ushort* hl = (const ushort*)(rp + 97);
            for (unsigned p = (unsigned)l; p < cr; p += 64u)
                s += (double)(bf2f(hl[p]) - 0.2f);
        }
        #pragma unroll
        for (int off = 32; off >= 1; off >>= 1) s += __shfl_down(s, off);
    } else {
        // ---- exact fallback: recompute the row's dots on the fly (never in
        // practice; >10-sigma events). Scalar-FMA recompute of the bf16 dots.
        int lo = -1, hi = 65535;
        while (hi - lo > 1) {
            unsigned midu = (unsigned)((lo + hi) >> 1);
            int c = 0;
            for (int cc = l; cc < N2; cc += 64) {
                const ushort* ar = A + (size_t)g * CDIM;
                const ushort* br = B + (size_t)cc * CDIM;
                float av = 0.f;
                for (int k = 0; k < CDIM; k++)
                    av = fmaf(bf2f(ar[k]), bf2f(br[k]), av);
                float dy = wkp1[2 * g] - kp2[2 * cc];
                float dx = wkp1[2 * g + 1] - kp2[2 * cc + 1];
                if (dy * dy + dx * dx <= thr2) av -= 5.0f;
                c += (int)(bits2key((unsigned)f2bf(av)) > midu);
            }
            #pragma unroll
            for (int off = 32; off >= 1; off >>= 1) c += __shfl_down(c, off);
            c = __shfl(c, 0);
            if (c >= 256) lo = (int)midu; else hi = (int)midu;
        }
        unsigned kt = (unsigned)hi;
        for (int cc = l; cc < N2; cc += 64) {
            const ushort* ar = A + (size_t)g * CDIM;
            const ushort* br = B + (size_t)cc * CDIM;
            float av = 0.f;
            for (int k = 0; k < CDIM; k++)
                av = fmaf(bf2f(ar[k]), bf2f(br[k]), av);
            float dy = wkp1[2 * g] - kp2[2 * cc];
            float dx = wkp1[2 * g + 1] - kp2[2 * cc + 1];
            if (dy * dy + dx * dx <= thr2) av -= 5.0f;
            unsigned h = (unsigned)f2bf(av);
            if (bits2key(h) > kt) {
                s += (double)fmaxf(bf2f(h) - 0.2f, 0.f);
                cgt++;
            }
        }
        ktb = key2bits(kt);
        #pragma unroll
        for (int off = 32; off >= 1; off >>= 1) {
            s += __shfl_down(s, off);
            cgt += __shfl_down(cgt, off);
        }
    }

    if (l == 0) {
        float vt = bf2f(ktb);
        double S = s + (double)(256 - cgt) * (double)fmaxf(vt - 0.2f, 0.0f);
        rloss[g] = (float)(S * (double)INV_DENOM);
    }
}

// ---------- final reduce: sum 2*N1 floats -> out[0] ----------
__global__ void reduce_kernel(const float* __restrict__ a, float* __restrict__ out) {
    const int t = threadIdx.x;
    float s = 0.f;
    for (int i = t; i < 2 * N1; i += 256) s += a[i];
    #pragma unroll
    for (int off = 32; off >= 1; off >>= 1) s += __shfl_down(s, off);
    __shared__ float ws[4];
    int wave = t >> 6, lane = t & 63;
    if (lane == 0) ws[wave] = s;
    __syncthreads();
    if (t == 0) out[0] = ws[0] + ws[1] + ws[2] + ws[3];
}

extern "C" void kernel_launch(void* const* d_in, const int* in_sizes, int n_in,
                              void* d_out, int out_size, void* d_ws, size_t ws_size,
                              hipStream_t stream) {
    const float* wkp1  = (const float*)d_in[1];
    const float* kp2   = (const float*)d_in[2];
    const float* kp1d  = (const float*)d_in[3];
    const float* kp2d  = (const float*)d_in[4];
    const float* desc2 = (const float*)d_in[5];
    float* out = (float*)d_out;

    ushort*   Abf   = (ushort*)d_ws;                        // 2 MB
    ushort*   Bbf   = Abf + (size_t)N1 * CDIM;              // 2 MB
    float*    loss  = (float*)(Bbf + (size_t)N2 * CDIM);    // 64 KB (pos | rows)
    float*    d2T   = loss + 2 * N1;                        // 2.4 MB
    unsigned* parts = (unsigned*)(d2T + (size_t)NPIX * CDIM); // 28 MB partial hists

    int n4 = N1 * CDIM / 4;
    int prep_elems = 2 * n4 + NPIX * CDIM;
    prep_kernel<<<(prep_elems + 255) / 256, 256, 0, stream>>>(kp1d, kp2d, desc2,
                                                              Abf, Bbf, d2T);

    pos_kernel<<<N1, 128, 0, stream>>>(wkp1, kp1d, d2T, loss);

    dim3 grid(NSPLIT, N1 / 128);    // 8 x 64 = 512 blocks, 2/CU
    gemm_kernel<<<grid, 256, 0, stream>>>(Abf, Bbf, wkp1, kp2, parts);

    select_kernel<<<N1 / 4, 256, 0, stream>>>(parts, Abf, Bbf, wkp1, kp2,
                                              loss + N1);

    reduce_kernel<<<1, 256, 0, stream>>>(loss, out);
}

// Round 4
// 179.910 us; speedup vs baseline: 1.0799x; 1.0799x over previous
//
#include <hip/hip_runtime.h>
#include <hip/hip_bf16.h>

#define N1 8192
#define N2 8192
#define CDIM 128
#define HC 60
#define WC 80
#define HIMG 480
#define WIMG 640
#define NPIX (HC * WC)
#define INV_DENOM (1.0f / (8192.0f * 256.0f))
#define THIBITS 0x4200u     // bf16 bits of 32.0
#define PADK 136            // LDS row stride (128 + 8 ushort): keeps 16B align

using bf16x8 = __attribute__((ext_vector_type(8))) short;
using f32x4  = __attribute__((ext_vector_type(4))) float;

__device__ __forceinline__ ushort f2bf(float f) {
    union { float f; unsigned u; } x; x.f = f;
    unsigned u = x.u;
    unsigned r = (u + 0x7FFFu + ((u >> 16) & 1u)) >> 16;
    return (ushort)r;
}
__device__ __forceinline__ float bf2f(unsigned bits) {
    union { unsigned u; float f; } x; x.u = bits << 16; return x.f;
}
__device__ __forceinline__ unsigned key2bits(unsigned k) {
    return k ^ ((k & 0x8000u) ? 0x8000u : 0xFFFFu);
}
__device__ __forceinline__ unsigned bits2key(unsigned h) {
    return h ^ ((h & 0x8000u) ? 0xFFFFu : 0x8000u);
}

// ---------- fused prep: cvt A, cvt B, transpose desc2 ----------
__global__ void prep_kernel(const float* __restrict__ kp1d,
                            const float* __restrict__ kp2d,
                            const float* __restrict__ desc2,
                            ushort* __restrict__ Abf, ushort* __restrict__ Bbf,
                            float* __restrict__ d2T) {
    const int n4 = N1 * CDIM / 4;        // 262144
    int i = blockIdx.x * blockDim.x + threadIdx.x;
    if (i < n4) {
        float4 v = ((const float4*)kp1d)[i];
        ushort4 o;
        o.x = f2bf(v.x); o.y = f2bf(v.y); o.z = f2bf(v.z); o.w = f2bf(v.w);
        ((ushort4*)Abf)[i] = o;
    } else if (i < 2 * n4) {
        int k = i - n4;
        float4 v = ((const float4*)kp2d)[k];
        ushort4 o;
        o.x = f2bf(v.x); o.y = f2bf(v.y); o.z = f2bf(v.z); o.w = f2bf(v.w);
        ((ushort4*)Bbf)[k] = o;
    } else {
        int e = i - 2 * n4;
        if (e < NPIX * CDIM) {
            int c = e / NPIX;
            int p = e - c * NPIX;
            d2T[(size_t)p * CDIM + c] = desc2[e];
        }
    }
}

// ---------- positive term (coalesced, plain store) ----------
__global__ void pos_kernel(const float* __restrict__ wkp1,
                           const float* __restrict__ kp1d,
                           const float* __restrict__ desc2T,
                           float* __restrict__ ploss) {
    const int i = blockIdx.x;
    const int c = threadIdx.x;            // 128 threads = 2 waves
    float y = wkp1[2 * i], x = wkp1[2 * i + 1];
    float py = fminf(fmaxf(y / (float)(HIMG - 1) * (float)(HC - 1), 0.0f), (float)(HC - 1));
    float px = fminf(fmaxf(x / (float)(WIMG - 1) * (float)(WC - 1), 0.0f), (float)(WC - 1));
    int y0 = min(max((int)floorf(py), 0), HC - 2);
    int x0 = min(max((int)floorf(px), 0), WC - 2);
    float wy = py - (float)y0;
    float wx = px - (float)x0;
    const int p00 = y0 * WC + x0;
    float v00 = desc2T[(size_t)p00 * CDIM + c];
    float v01 = desc2T[(size_t)(p00 + 1) * CDIM + c];
    float v10 = desc2T[(size_t)(p00 + WC) * CDIM + c];
    float v11 = desc2T[(size_t)(p00 + WC + 1) * CDIM + c];
    float v = v00 * (1.0f - wy) * (1.0f - wx) + v01 * (1.0f - wy) * wx
            + v10 * wy * (1.0f - wx) + v11 * wy * wx;
    float a = kp1d[(size_t)i * CDIM + c];
    float s2 = v * v, sav = a * v;
    #pragma unroll
    for (int off = 32; off >= 1; off >>= 1) {
        s2  += __shfl_down(s2, off);
        sav += __shfl_down(sav, off);
    }
    __shared__ float p2[2], pav[2];
    int wave = threadIdx.x >> 6, lane = threadIdx.x & 63;
    if (lane == 0) { p2[wave] = s2; pav[wave] = sav; }
    __syncthreads();
    if (threadIdx.x == 0) {
        float nrm = sqrtf(p2[0] + p2[1]);
        float pd = (pav[0] + pav[1]) / fmaxf(nrm, 1e-12f);
        float l = fmaxf(1.0f - pd, 0.0f) * (256.0f / 3.0f);
        ploss[i] = l * INV_DENOM;
    }
}

// ---------- masked GEMM, LDS-staged, BYTE-coded dots (R4) ----------
// R3 post-mortem: unstaged B-loads + per-candidate LDS atomics in the epilogue
// doubled gemm time. R4 keeps R2's staged K-loop verbatim and halves the
// write traffic instead: store a BYTE code per value (u = bf16bits - 0x4141;
// u<0xC0 -> bin code u; v>32 -> 0xC1; else 0xC0). The rare >32 values
// (~0.25%) need no value list: accumulate sum(v*4) + count as INTEGER LDS
// atomics (~40/block; every bf16 >= 32 is a multiple of 0.25 -> exact,
// commutative -> deterministic) and write a per-(block,row) uint2 record.
// 64 MB codes + 4 MB records replace the 128 MB ushort dots.
__global__ __launch_bounds__(256, 2)
void gemm_kernel(const ushort* __restrict__ A, const ushort* __restrict__ B,
                 const float* __restrict__ wkp1, const float* __restrict__ kp2,
                 unsigned char* __restrict__ dots8, uint2* __restrict__ recs) {
    __shared__ ushort sA[128 * PADK];     // 34 KB
    __shared__ ushort sB[128 * PADK];     // 34 KB
    __shared__ float s_w[256], s_k[256];  // 2 KB coords
    __shared__ unsigned ssum[128], scnt[128];  // 1 KB hi fixed-point sums

    const int t = threadIdx.x;
    const int n0 = blockIdx.x * 128;
    const int m0 = blockIdx.y * 128;

    s_w[t] = wkp1[2 * m0 + t];
    s_k[t] = kp2[2 * n0 + t];
    if (t < 128) { ssum[t] = 0u; scnt[t] = 0u; }

    {
        const uint4* Ag = (const uint4*)(A + (size_t)m0 * CDIM);
        const uint4* Bg = (const uint4*)(B + (size_t)n0 * CDIM);
        #pragma unroll
        for (int r = 0; r < 8; r++) {
            int g = t + 256 * r;          // uint4 index 0..2047
            int row = g >> 4;
            int k8 = g & 15;
            uint4 va = Ag[g];
            uint4 vb = Bg[g];
            *(uint4*)(sA + row * PADK + k8 * 8) = va;
            *(uint4*)(sB + row * PADK + k8 * 8) = vb;
        }
    }
    __syncthreads();

    const int lane = t & 63;
    const int wave = t >> 6;
    const int wm = wave >> 1, wn = wave & 1;
    const int lrow = lane & 15, quad = lane >> 4;

    f32x4 acc[4][4];
    #pragma unroll
    for (int i = 0; i < 4; i++)
        #pragma unroll
        for (int j = 0; j < 4; j++) acc[i][j] = (f32x4){0.f, 0.f, 0.f, 0.f};

    #pragma unroll
    for (int kit = 0; kit < 4; kit++) {
        const int kk = kit * 32 + quad * 8;
        bf16x8 af[4], bfr[4];
        #pragma unroll
        for (int mt = 0; mt < 4; mt++)
            af[mt] = *(const bf16x8*)(sA + (wm * 64 + mt * 16 + lrow) * PADK + kk);
        #pragma unroll
        for (int nt = 0; nt < 4; nt++)
            bfr[nt] = *(const bf16x8*)(sB + (wn * 64 + nt * 16 + lrow) * PADK + kk);
        #pragma unroll
        for (int mt = 0; mt < 4; mt++)
            #pragma unroll
            for (int nt = 0; nt < 4; nt++)
                acc[mt][nt] = __builtin_amdgcn_mfma_f32_16x16x32_bf16(
                    af[mt], bfr[nt], acc[mt][nt], 0, 0, 0);
    }

    float ky[4], kx[4];
    #pragma unroll
    for (int nt = 0; nt < 4; nt++) {
        int jl = wn * 64 + nt * 16 + lrow;
        ky[nt] = s_k[2 * jl]; kx[nt] = s_k[2 * jl + 1];
    }
    const float thr = 2.0f * sqrtf(32.0f) + 0.1f;
    const float thr2 = thr * thr;
    const size_t colbase = (size_t)(n0 + wn * 64 + lrow * 4);
    #pragma unroll
    for (int mt = 0; mt < 4; mt++) {
        #pragma unroll
        for (int r = 0; r < 4; r++) {
            const int il = wm * 64 + mt * 16 + quad * 4 + r;      // local row
            const int i = m0 + il;
            const float wy = s_w[2 * il], wx = s_w[2 * il + 1];
            unsigned codes = 0u;
            #pragma unroll
            for (int nt = 0; nt < 4; nt++) {
                float dy = wy - ky[nt], dx = wx - kx[nt];
                float v = acc[mt][nt][r];
                if (dy * dy + dx * dx <= thr2) v -= 5.0f;
                unsigned h = (unsigned)f2bf(v);
                unsigned u = h - 0x4141u;
                unsigned c = (u < 0xC0u) ? u : ((u < 0x3EBFu) ? 0xC1u : 0xC0u);
                if ((u - 0xC0u) < 0x3DFFu) {          // v > 32: rare (~0.25%)
                    atomicAdd(&ssum[il], (unsigned)(int)(bf2f(h) * 4.0f));
                    atomicAdd(&scnt[il], 1u);
                }
                codes |= c << (8 * nt);
            }
            *(unsigned*)(dots8 + (size_t)i * N2 + colbase) = codes;
        }
    }
    __syncthreads();
    if (t < 128)
        recs[((size_t)blockIdx.y * 64 + blockIdx.x) * 128 + t] =
            make_uint2(ssum[t], scnt[t]);
}

// ---------- per-row top-256 hinge via byte-code histogram (R4) ----------
// One block per row. Byte codes ARE the bin indices: one LDS atomicAdd per
// value (dummy-slot for the ~85% non-candidates -- conflict-free 2-way), then
// R2's proven suffix-scan / threshold-find / f64 per-bin sums verbatim. The
// >32 contribution is 0.25*S4 - 0.2*nhi from the merged integer records
// (exact in f64 -> deterministic). Fallback (tot<256 | nhi>255; >10-sigma)
// recomputes the row's dots from Abf/Bbf on the fly; dots stays byte-only.
__global__ __launch_bounds__(256)
void select_kernel(const unsigned char* __restrict__ dots8,
                   const uint2* __restrict__ recs,
                   const ushort* __restrict__ A, const ushort* __restrict__ B,
                   const float* __restrict__ wkp1, const float* __restrict__ kp2,
                   float* __restrict__ rloss) {
    const int g = blockIdx.x;                    // global row
    const int t = threadIdx.x;
    const int l = t & 63;

    __shared__ unsigned hist[192];
    __shared__ unsigned dmy[64];

    if (t < 192) hist[t] = 0u;
    __syncthreads();

    const uint4* rp = (const uint4*)(dots8 + (size_t)g * N2);   // 512 uint4
    #pragma unroll
    for (int j = 0; j < 2; j++) {
        uint4 w = rp[t + 256 * j];
        unsigned xs[4] = {w.x, w.y, w.z, w.w};
        #pragma unroll
        for (int q = 0; q < 4; q++) {
            unsigned x = xs[q];
            #pragma unroll
            for (int b = 0; b < 4; b++) {
                unsigned code = (x >> (8 * b)) & 0xFFu;
                unsigned* p = (code < 192u) ? &hist[code] : &dmy[l];
                atomicAdd(p, 1u);
            }
        }
    }
    __syncthreads();
    if (t >= 64) return;                         // wave0 selects; no barriers follow

    // merge the 64 per-column-block hi records for this row
    const int mtile = g >> 7, rowin = g & 127;
    uint2 rec = recs[((size_t)mtile * 64 + l) * 128 + rowin];
    unsigned S4 = rec.x, nhi = rec.y;
    #pragma unroll
    for (int off = 32; off >= 1; off >>= 1) {
        S4  += __shfl_xor(S4, off);
        nhi += __shfl_xor(nhi, off);
    }

    unsigned c0 = hist[l], c1 = hist[64 + l], c2 = hist[128 + l];

    // inclusive suffix-scan across lanes for each 64-bin chunk
    unsigned s0i = c0, s1i = c1, s2i = c2;
    #pragma unroll
    for (int off = 1; off < 64; off <<= 1) {
        unsigned t0 = __shfl_down(s0i, off);
        unsigned t1 = __shfl_down(s1i, off);
        unsigned t2 = __shfl_down(s2i, off);
        if (l + off < 64) { s0i += t0; s1i += t1; s2i += t2; }
    }
    const unsigned T0 = __shfl(s0i, 0), T1 = __shfl(s1i, 0), T2 = __shfl(s2i, 0);
    const unsigned tot = nhi + T0 + T1 + T2;     // count of values > 12.0

    const unsigned Ce0 = nhi + T1 + T2 + (s0i - c0);
    const unsigned Ce1 = nhi + T2 + (s1i - c1);
    const unsigned Ce2 = nhi + (s2i - c2);

    const bool ok = (tot >= 256u) && (nhi <= 255u);

    const float thr = 2.0f * sqrtf(32.0f) + 0.1f;
    const float thr2 = thr * thr;

    unsigned ktb;            // bf16 bits of 256th-largest (attained)
    double s = 0.0;
    int cgt = 0;

    if (ok) {
        unsigned long long m0 = __ballot(Ce0 < 256u);
        unsigned long long m1 = __ballot(Ce1 < 256u);
        unsigned long long m2 = __ballot(Ce2 < 256u);
        int bmin; unsigned cg;
        if (m0) { int fl = __ffsll(m0) - 1; bmin = fl;       cg = __shfl(Ce0, fl); }
        else if (m1) { int fl = __ffsll(m1) - 1; bmin = 64 + fl;  cg = __shfl(Ce1, fl); }
        else { int fl = __ffsll(m2) - 1; bmin = 128 + fl; cg = __shfl(Ce2, fl); }
        ktb = 0x4141u + (unsigned)bmin;
        cgt = (int)cg;
        // per-bin hinge sums: cnt * (f32)(val - 0.2f), exact in f64
        if (l > bmin)       s += (double)c0 * (double)(bf2f(0x4141u + (unsigned)l) - 0.2f);
        if (64 + l > bmin)  s += (double)c1 * (double)(bf2f(0x4141u + 64u + (unsigned)l) - 0.2f);
        if (128 + l > bmin) s += (double)c2 * (double)(bf2f(0x4141u + 128u + (unsigned)l) - 0.2f);
        #pragma unroll
        for (int off = 32; off >= 1; off >>= 1) s += __shfl_down(s, off);
        // >32 values: all above threshold; exact fixed-point sum
        if (l == 0)
            s += 0.25 * (double)S4 - (double)0.2f * (double)nhi;
    } else {
        // ---- exact fallback: recompute the row's dots on the fly (never in
        // practice; >10-sigma events). Scalar-FMA recompute of the bf16 dots.
        int lo = -1, hi = 65535;
        while (hi - lo > 1) {
            unsigned midu = (unsigned)((lo + hi) >> 1);
            int c = 0;
            for (int cc = l; cc < N2; cc += 64) {
                const ushort* ar = A + (size_t)g * CDIM;
                const ushort* br = B + (size_t)cc * CDIM;
                float av = 0.f;
                for (int k = 0; k < CDIM; k++)
                    av = fmaf(bf2f(ar[k]), bf2f(br[k]), av);
                float dy = wkp1[2 * g] - kp2[2 * cc];
                float dx = wkp1[2 * g + 1] - kp2[2 * cc + 1];
                if (dy * dy + dx * dx <= thr2) av -= 5.0f;
                c += (int)(bits2key((unsigned)f2bf(av)) > midu);
            }
            #pragma unroll
            for (int off = 32; off >= 1; off >>= 1) c += __shfl_down(c, off);
            c = __shfl(c, 0);
            if (c >= 256) lo = (int)midu; else hi = (int)midu;
        }
        unsigned kt = (unsigned)hi;
        for (int cc = l; cc < N2; cc += 64) {
            const ushort* ar = A + (size_t)g * CDIM;
            const ushort* br = B + (size_t)cc * CDIM;
            float av = 0.f;
            for (int k = 0; k < CDIM; k++)
                av = fmaf(bf2f(ar[k]), bf2f(br[k]), av);
            float dy = wkp1[2 * g] - kp2[2 * cc];
            float dx = wkp1[2 * g + 1] - kp2[2 * cc + 1];
            if (dy * dy + dx * dx <= thr2) av -= 5.0f;
            unsigned h = (unsigned)f2bf(av);
            if (bits2key(h) > kt) {
                s += (double)fmaxf(bf2f(h) - 0.2f, 0.f);
                cgt++;
            }
        }
        ktb = key2bits(kt);
        #pragma unroll
        for (int off = 32; off >= 1; off >>= 1) {
            s += __shfl_down(s, off);
            cgt += __shfl_down(cgt, off);
        }
    }

    if (l == 0) {
        float vt = bf2f(ktb);
        double S = s + (double)(256 - cgt) * (double)fmaxf(vt - 0.2f, 0.0f);
        rloss[g] = (float)(S * (double)INV_DENOM);
    }
}

// ---------- final reduce: sum 2*N1 floats -> out[0] ----------
__global__ void reduce_kernel(const float* __restrict__ a, float* __restrict__ out) {
    const int t = threadIdx.x;
    float s = 0.f;
    for (int i = t; i < 2 * N1; i += 256) s += a[i];
    #pragma unroll
    for (int off = 32; off >= 1; off >>= 1) s += __shfl_down(s, off);
    __shared__ float ws[4];
    int wave = t >> 6, lane = t & 63;
    if (lane == 0) ws[wave] = s;
    __syncthreads();
    if (t == 0) out[0] = ws[0] + ws[1] + ws[2] + ws[3];
}

extern "C" void kernel_launch(void* const* d_in, const int* in_sizes, int n_in,
                              void* d_out, int out_size, void* d_ws, size_t ws_size,
                              hipStream_t stream) {
    const float* wkp1  = (const float*)d_in[1];
    const float* kp2   = (const float*)d_in[2];
    const float* kp1d  = (const float*)d_in[3];
    const float* kp2d  = (const float*)d_in[4];
    const float* desc2 = (const float*)d_in[5];
    float* out = (float*)d_out;

    ushort*        Abf   = (ushort*)d_ws;                       // 2 MB
    ushort*        Bbf   = Abf + (size_t)N1 * CDIM;             // 2 MB
    float*         loss  = (float*)(Bbf + (size_t)N2 * CDIM);   // 64 KB (pos | rows)
    float*         d2T   = loss + 2 * N1;                       // 2.4 MB
    uint2*         recs  = (uint2*)(d2T + (size_t)NPIX * CDIM); // 4 MB hi records
    unsigned char* dots8 = (unsigned char*)(recs + (size_t)64 * 64 * 128); // 64 MB

    int n4 = N1 * CDIM / 4;
    int prep_elems = 2 * n4 + NPIX * CDIM;
    prep_kernel<<<(prep_elems + 255) / 256, 256, 0, stream>>>(kp1d, kp2d, desc2,
                                                              Abf, Bbf, d2T);

    pos_kernel<<<N1, 128, 0, stream>>>(wkp1, kp1d, d2T, loss);

    dim3 grid(N2 / 128, N1 / 128);      // 64 x 64
    gemm_kernel<<<grid, 256, 0, stream>>>(Abf, Bbf, wkp1, kp2, dots8, recs);

    select_kernel<<<N1, 256, 0, stream>>>(dots8, recs, Abf, Bbf, wkp1, kp2,
                                          loss + N1);

    reduce_kernel<<<1, 256, 0, stream>>>(loss, out);
}

// Round 5
// 172.205 us; speedup vs baseline: 1.1282x; 1.0447x over previous
//
#include <hip/hip_runtime.h>
#include <hip/hip_bf16.h>

#define N1 8192
#define N2 8192
#define CDIM 128
#define HC 60
#define WC 80
#define HIMG 480
#define WIMG 640
#define NPIX (HC * WC)
#define INV_DENOM (1.0f / (8192.0f * 256.0f))
#define THIBITS 0x4200u     // bf16 bits of 32.0
#define PADK 136            // LDS row stride (128 + 8 ushort): keeps 16B align

using bf16x8 = __attribute__((ext_vector_type(8))) short;
using f32x4  = __attribute__((ext_vector_type(4))) float;

__device__ __forceinline__ ushort f2bf(float f) {
    union { float f; unsigned u; } x; x.f = f;
    unsigned u = x.u;
    unsigned r = (u + 0x7FFFu + ((u >> 16) & 1u)) >> 16;
    return (ushort)r;
}
__device__ __forceinline__ float bf2f(unsigned bits) {
    union { unsigned u; float f; } x; x.u = bits << 16; return x.f;
}
__device__ __forceinline__ unsigned key2bits(unsigned k) {
    return k ^ ((k & 0x8000u) ? 0x8000u : 0xFFFFu);
}
__device__ __forceinline__ unsigned bits2key(unsigned h) {
    return h ^ ((h & 0x8000u) ? 0xFFFFu : 0x8000u);
}

// ---------- fused prep: cvt A, cvt B, transpose desc2 ----------
__global__ void prep_kernel(const float* __restrict__ kp1d,
                            const float* __restrict__ kp2d,
                            const float* __restrict__ desc2,
                            ushort* __restrict__ Abf, ushort* __restrict__ Bbf,
                            float* __restrict__ d2T) {
    const int n4 = N1 * CDIM / 4;        // 262144
    int i = blockIdx.x * blockDim.x + threadIdx.x;
    if (i < n4) {
        float4 v = ((const float4*)kp1d)[i];
        ushort4 o;
        o.x = f2bf(v.x); o.y = f2bf(v.y); o.z = f2bf(v.z); o.w = f2bf(v.w);
        ((ushort4*)Abf)[i] = o;
    } else if (i < 2 * n4) {
        int k = i - n4;
        float4 v = ((const float4*)kp2d)[k];
        ushort4 o;
        o.x = f2bf(v.x); o.y = f2bf(v.y); o.z = f2bf(v.z); o.w = f2bf(v.w);
        ((ushort4*)Bbf)[k] = o;
    } else {
        int e = i - 2 * n4;
        if (e < NPIX * CDIM) {
            int c = e / NPIX;
            int p = e - c * NPIX;
            d2T[(size_t)p * CDIM + c] = desc2[e];
        }
    }
}

// ---------- positive term (coalesced, plain store) ----------
__global__ void pos_kernel(const float* __restrict__ wkp1,
                           const float* __restrict__ kp1d,
                           const float* __restrict__ desc2T,
                           float* __restrict__ ploss) {
    const int i = blockIdx.x;
    const int c = threadIdx.x;            // 128 threads = 2 waves
    float y = wkp1[2 * i], x = wkp1[2 * i + 1];
    float py = fminf(fmaxf(y / (float)(HIMG - 1) * (float)(HC - 1), 0.0f), (float)(HC - 1));
    float px = fminf(fmaxf(x / (float)(WIMG - 1) * (float)(WC - 1), 0.0f), (float)(WC - 1));
    int y0 = min(max((int)floorf(py), 0), HC - 2);
    int x0 = min(max((int)floorf(px), 0), WC - 2);
    float wy = py - (float)y0;
    float wx = px - (float)x0;
    const int p00 = y0 * WC + x0;
    float v00 = desc2T[(size_t)p00 * CDIM + c];
    float v01 = desc2T[(size_t)(p00 + 1) * CDIM + c];
    float v10 = desc2T[(size_t)(p00 + WC) * CDIM + c];
    float v11 = desc2T[(size_t)(p00 + WC + 1) * CDIM + c];
    float v = v00 * (1.0f - wy) * (1.0f - wx) + v01 * (1.0f - wy) * wx
            + v10 * wy * (1.0f - wx) + v11 * wy * wx;
    float a = kp1d[(size_t)i * CDIM + c];
    float s2 = v * v, sav = a * v;
    #pragma unroll
    for (int off = 32; off >= 1; off >>= 1) {
        s2  += __shfl_down(s2, off);
        sav += __shfl_down(sav, off);
    }
    __shared__ float p2[2], pav[2];
    int wave = threadIdx.x >> 6, lane = threadIdx.x & 63;
    if (lane == 0) { p2[wave] = s2; pav[wave] = sav; }
    __syncthreads();
    if (threadIdx.x == 0) {
        float nrm = sqrtf(p2[0] + p2[1]);
        float pd = (pav[0] + pav[1]) / fmaxf(nrm, 1e-12f);
        float l = fmaxf(1.0f - pd, 0.0f) * (256.0f / 3.0f);
        ploss[i] = l * INV_DENOM;
    }
}

// ---------- masked GEMM, LDS-staged, BYTE-coded dots (R5) ----------
// R4 post-mortem: byte codes halved writes but the epilogue's 64 per-value
// divergent atomic branches + 2-cndmask ternaries added ~65% VALU cycles
// (gemm 47.5->75us). R5 keeps R4's encoding/records/select but makes the
// epilogue branchless: code = med3_i32(h-0x4141, -1, 0xC1) (one min+max;
// all bytes >= 0xC0 are "not binned" in select so low/hi sentinels need no
// distinction), and the rare >32 fixed-point accumulation sits behind ONE
// per-(mt,r)-group __any gate (~7% taken) instead of per-value branches.
// Stores issue before the gate so they never wait on the LDS atomics.
__global__ __launch_bounds__(256, 2)
void gemm_kernel(const ushort* __restrict__ A, const ushort* __restrict__ B,
                 const float* __restrict__ wkp1, const float* __restrict__ kp2,
                 unsigned char* __restrict__ dots8, uint2* __restrict__ recs) {
    __shared__ ushort sA[128 * PADK];     // 34 KB
    __shared__ ushort sB[128 * PADK];     // 34 KB
    __shared__ float s_w[256], s_k[256];  // 2 KB coords
    __shared__ unsigned ssum[128], scnt[128];  // 1 KB hi fixed-point sums

    const int t = threadIdx.x;
    const int n0 = blockIdx.x * 128;
    const int m0 = blockIdx.y * 128;

    s_w[t] = wkp1[2 * m0 + t];
    s_k[t] = kp2[2 * n0 + t];
    if (t < 128) { ssum[t] = 0u; scnt[t] = 0u; }

    {
        const uint4* Ag = (const uint4*)(A + (size_t)m0 * CDIM);
        const uint4* Bg = (const uint4*)(B + (size_t)n0 * CDIM);
        #pragma unroll
        for (int r = 0; r < 8; r++) {
            int g = t + 256 * r;          // uint4 index 0..2047
            int row = g >> 4;
            int k8 = g & 15;
            uint4 va = Ag[g];
            uint4 vb = Bg[g];
            *(uint4*)(sA + row * PADK + k8 * 8) = va;
            *(uint4*)(sB + row * PADK + k8 * 8) = vb;
        }
    }
    __syncthreads();

    const int lane = t & 63;
    const int wave = t >> 6;
    const int wm = wave >> 1, wn = wave & 1;
    const int lrow = lane & 15, quad = lane >> 4;

    f32x4 acc[4][4];
    #pragma unroll
    for (int i = 0; i < 4; i++)
        #pragma unroll
        for (int j = 0; j < 4; j++) acc[i][j] = (f32x4){0.f, 0.f, 0.f, 0.f};

    #pragma unroll
    for (int kit = 0; kit < 4; kit++) {
        const int kk = kit * 32 + quad * 8;
        bf16x8 af[4], bfr[4];
        #pragma unroll
        for (int mt = 0; mt < 4; mt++)
            af[mt] = *(const bf16x8*)(sA + (wm * 64 + mt * 16 + lrow) * PADK + kk);
        #pragma unroll
        for (int nt = 0; nt < 4; nt++)
            bfr[nt] = *(const bf16x8*)(sB + (wn * 64 + nt * 16 + lrow) * PADK + kk);
        #pragma unroll
        for (int mt = 0; mt < 4; mt++)
            #pragma unroll
            for (int nt = 0; nt < 4; nt++)
                acc[mt][nt] = __builtin_amdgcn_mfma_f32_16x16x32_bf16(
                    af[mt], bfr[nt], acc[mt][nt], 0, 0, 0);
    }

    float ky[4], kx[4];
    #pragma unroll
    for (int nt = 0; nt < 4; nt++) {
        int jl = wn * 64 + nt * 16 + lrow;
        ky[nt] = s_k[2 * jl]; kx[nt] = s_k[2 * jl + 1];
    }
    const float thr = 2.0f * sqrtf(32.0f) + 0.1f;
    const float thr2 = thr * thr;
    const size_t colbase = (size_t)(n0 + wn * 64 + lrow * 4);
    #pragma unroll
    for (int mt = 0; mt < 4; mt++) {
        #pragma unroll
        for (int r = 0; r < 4; r++) {
            const int il = wm * 64 + mt * 16 + quad * 4 + r;      // local row
            const int i = m0 + il;
            const float wy = s_w[2 * il], wx = s_w[2 * il + 1];
            unsigned codes = 0u;
            unsigned hbits[4];
            bool hi[4];
            bool anyhi = false;
            #pragma unroll
            for (int nt = 0; nt < 4; nt++) {
                float dy = wy - ky[nt], dx = wx - kx[nt];
                float v = acc[mt][nt][r];
                v = (dy * dy + dx * dx <= thr2) ? v - 5.0f : v;
                unsigned h = (unsigned)f2bf(v);
                hbits[nt] = h;
                int u = (int)h - 0x4141;
                int c = min(max(u, -1), 0xC1);      // v_med3_i32: clamp
                codes |= ((unsigned)c & 0xFFu) << (8 * nt);
                bool ih = ((unsigned)(u - 0xC0) < 0x3D80u);  // v > 32, positive
                hi[nt] = ih;
                anyhi |= ih;
            }
            *(unsigned*)(dots8 + (size_t)i * N2 + colbase) = codes;
            if (__any(anyhi)) {                     // ~7% of groups
                #pragma unroll
                for (int nt = 0; nt < 4; nt++)
                    if (hi[nt]) {
                        atomicAdd(&ssum[il], (unsigned)(int)(bf2f(hbits[nt]) * 4.0f));
                        atomicAdd(&scnt[il], 1u);
                    }
            }
        }
    }
    __syncthreads();
    if (t < 128)
        recs[((size_t)blockIdx.y * 64 + blockIdx.x) * 128 + t] =
            make_uint2(ssum[t], scnt[t]);
}

// ---------- per-row top-256 hinge via byte-code histogram (R4, unchanged) ----------
// One block per row. Byte codes ARE the bin indices: one LDS atomicAdd per
// value (dummy-slot for non-candidates), then the proven suffix-scan /
// threshold-find / f64 per-bin sums. The >32 contribution is 0.25*S4-0.2*nhi
// from merged integer records (exact -> deterministic). Fallback (tot<256 |
// nhi>255; >10-sigma) recomputes the row's dots from Abf/Bbf on the fly.
__global__ __launch_bounds__(256)
void select_kernel(const unsigned char* __restrict__ dots8,
                   const uint2* __restrict__ recs,
                   const ushort* __restrict__ A, const ushort* __restrict__ B,
                   const float* __restrict__ wkp1, const float* __restrict__ kp2,
                   float* __restrict__ rloss) {
    const int g = blockIdx.x;                    // global row
    const int t = threadIdx.x;
    const int l = t & 63;

    __shared__ unsigned hist[192];
    __shared__ unsigned dmy[64];

    if (t < 192) hist[t] = 0u;
    __syncthreads();

    const uint4* rp = (const uint4*)(dots8 + (size_t)g * N2);   // 512 uint4
    #pragma unroll
    for (int j = 0; j < 2; j++) {
        uint4 w = rp[t + 256 * j];
        unsigned xs[4] = {w.x, w.y, w.z, w.w};
        #pragma unroll
        for (int q = 0; q < 4; q++) {
            unsigned x = xs[q];
            #pragma unroll
            for (int b = 0; b < 4; b++) {
                unsigned code = (x >> (8 * b)) & 0xFFu;
                unsigned* p = (code < 192u) ? &hist[code] : &dmy[l];
                atomicAdd(p, 1u);
            }
        }
    }
    __syncthreads();
    if (t >= 64) return;                         // wave0 selects; no barriers follow

    // merge the 64 per-column-block hi records for this row
    const int mtile = g >> 7, rowin = g & 127;
    uint2 rec = recs[((size_t)mtile * 64 + l) * 128 + rowin];
    unsigned S4 = rec.x, nhi = rec.y;
    #pragma unroll
    for (int off = 32; off >= 1; off >>= 1) {
        S4  += __shfl_xor(S4, off);
        nhi += __shfl_xor(nhi, off);
    }

    unsigned c0 = hist[l], c1 = hist[64 + l], c2 = hist[128 + l];

    // inclusive suffix-scan across lanes for each 64-bin chunk
    unsigned s0i = c0, s1i = c1, s2i = c2;
    #pragma unroll
    for (int off = 1; off < 64; off <<= 1) {
        unsigned t0 = __shfl_down(s0i, off);
        unsigned t1 = __shfl_down(s1i, off);
        unsigned t2 = __shfl_down(s2i, off);
        if (l + off < 64) { s0i += t0; s1i += t1; s2i += t2; }
    }
    const unsigned T0 = __shfl(s0i, 0), T1 = __shfl(s1i, 0), T2 = __shfl(s2i, 0);
    const unsigned tot = nhi + T0 + T1 + T2;     // count of values > 12.0

    const unsigned Ce0 = nhi + T1 + T2 + (s0i - c0);
    const unsigned Ce1 = nhi + T2 + (s1i - c1);
    const unsigned Ce2 = nhi + (s2i - c2);

    const bool ok = (tot >= 256u) && (nhi <= 255u);

    const float thr = 2.0f * sqrtf(32.0f) + 0.1f;
    const float thr2 = thr * thr;

    unsigned ktb;            // bf16 bits of 256th-largest (attained)
    double s = 0.0;
    int cgt = 0;

    if (ok) {
        unsigned long long m0 = __ballot(Ce0 < 256u);
        unsigned long long m1 = __ballot(Ce1 < 256u);
        unsigned long long m2 = __ballot(Ce2 < 256u);
        int bmin; unsigned cg;
        if (m0) { int fl = __ffsll(m0) - 1; bmin = fl;       cg = __shfl(Ce0, fl); }
        else if (m1) { int fl = __ffsll(m1) - 1; bmin = 64 + fl;  cg = __shfl(Ce1, fl); }
        else { int fl = __ffsll(m2) - 1; bmin = 128 + fl; cg = __shfl(Ce2, fl); }
        ktb = 0x4141u + (unsigned)bmin;
        cgt = (int)cg;
        // per-bin hinge sums: cnt * (f32)(val - 0.2f), exact in f64
        if (l > bmin)       s += (double)c0 * (double)(bf2f(0x4141u + (unsigned)l) - 0.2f);
        if (64 + l > bmin)  s += (double)c1 * (double)(bf2f(0x4141u + 64u + (unsigned)l) - 0.2f);
        if (128 + l > bmin) s += (double)c2 * (double)(bf2f(0x4141u + 128u + (unsigned)l) - 0.2f);
        #pragma unroll
        for (int off = 32; off >= 1; off >>= 1) s += __shfl_down(s, off);
        // >32 values: all above threshold; exact fixed-point sum
        if (l == 0)
            s += 0.25 * (double)S4 - (double)0.2f * (double)nhi;
    } else {
        // ---- exact fallback: recompute the row's dots on the fly (never in
        // practice; >10-sigma events). Scalar-FMA recompute of the bf16 dots.
        int lo = -1, hi = 65535;
        while (hi - lo > 1) {
            unsigned midu = (unsigned)((lo + hi) >> 1);
            int c = 0;
            for (int cc = l; cc < N2; cc += 64) {
                const ushort* ar = A + (size_t)g * CDIM;
                const ushort* br = B + (size_t)cc * CDIM;
                float av = 0.f;
                for (int k = 0; k < CDIM; k++)
                    av = fmaf(bf2f(ar[k]), bf2f(br[k]), av);
                float dy = wkp1[2 * g] - kp2[2 * cc];
                float dx = wkp1[2 * g + 1] - kp2[2 * cc + 1];
                if (dy * dy + dx * dx <= thr2) av -= 5.0f;
                c += (int)(bits2key((unsigned)f2bf(av)) > midu);
            }
            #pragma unroll
            for (int off = 32; off >= 1; off >>= 1) c += __shfl_down(c, off);
            c = __shfl(c, 0);
            if (c >= 256) lo = (int)midu; else hi = (int)midu;
        }
        unsigned kt = (unsigned)hi;
        for (int cc = l; cc < N2; cc += 64) {
            const ushort* ar = A + (size_t)g * CDIM;
            const ushort* br = B + (size_t)cc * CDIM;
            float av = 0.f;
            for (int k = 0; k < CDIM; k++)
                av = fmaf(bf2f(ar[k]), bf2f(br[k]), av);
            float dy = wkp1[2 * g] - kp2[2 * cc];
            float dx = wkp1[2 * g + 1] - kp2[2 * cc + 1];
            if (dy * dy + dx * dx <= thr2) av -= 5.0f;
            unsigned h = (unsigned)f2bf(av);
            if (bits2key(h) > kt) {
                s += (double)fmaxf(bf2f(h) - 0.2f, 0.f);
                cgt++;
            }
        }
        ktb = key2bits(kt);
        #pragma unroll
        for (int off = 32; off >= 1; off >>= 1) {
            s += __shfl_down(s, off);
            cgt += __shfl_down(cgt, off);
        }
    }

    if (l == 0) {
        float vt = bf2f(ktb);
        double S = s + (double)(256 - cgt) * (double)fmaxf(vt - 0.2f, 0.0f);
        rloss[g] = (float)(S * (double)INV_DENOM);
    }
}

// ---------- final reduce: sum 2*N1 floats -> out[0] ----------
__global__ void reduce_kernel(const float* __restrict__ a, float* __restrict__ out) {
    const int t = threadIdx.x;
    float s = 0.f;
    for (int i = t; i < 2 * N1; i += 256) s += a[i];
    #pragma unroll
    for (int off = 32; off >= 1; off >>= 1) s += __shfl_down(s, off);
    __shared__ float ws[4];
    int wave = t >> 6, lane = t & 63;
    if (lane == 0) ws[wave] = s;
    __syncthreads();
    if (t == 0) out[0] = ws[0] + ws[1] + ws[2] + ws[3];
}

extern "C" void kernel_launch(void* const* d_in, const int* in_sizes, int n_in,
                              void* d_out, int out_size, void* d_ws, size_t ws_size,
                              hipStream_t stream) {
    const float* wkp1  = (const float*)d_in[1];
    const float* kp2   = (const float*)d_in[2];
    const float* kp1d  = (const float*)d_in[3];
    const float* kp2d  = (const float*)d_in[4];
    const float* desc2 = (const float*)d_in[5];
    float* out = (float*)d_out;

    ushort*        Abf   = (ushort*)d_ws;                       // 2 MB
    ushort*        Bbf   = Abf + (size_t)N1 * CDIM;             // 2 MB
    float*         loss  = (float*)(Bbf + (size_t)N2 * CDIM);   // 64 KB (pos | rows)
    float*         d2T   = loss + 2 * N1;                       // 2.4 MB
    uint2*         recs  = (uint2*)(d2T + (size_t)NPIX * CDIM); // 4 MB hi records
    unsigned char* dots8 = (unsigned char*)(recs + (size_t)64 * 64 * 128); // 64 MB

    int n4 = N1 * CDIM / 4;
    int prep_elems = 2 * n4 + NPIX * CDIM;
    prep_kernel<<<(prep_elems + 255) / 256, 256, 0, stream>>>(kp1d, kp2d, desc2,
                                                              Abf, Bbf, d2T);

    pos_kernel<<<N1, 128, 0, stream>>>(wkp1, kp1d, d2T, loss);

    dim3 grid(N2 / 128, N1 / 128);      // 64 x 64
    gemm_kernel<<<grid, 256, 0, stream>>>(Abf, Bbf, wkp1, kp2, dots8, recs);

    select_kernel<<<N1, 256, 0, stream>>>(dots8, recs, Abf, Bbf, wkp1, kp2,
                                          loss + N1);

    reduce_kernel<<<1, 256, 0, stream>>>(loss, out);
}